// Round 2
// baseline (35256.363 us; speedup 1.0000x reference)
//
#include <hip/hip_runtime.h>
#include <math.h>

#define BATCH 128
#define CCH 5
#define SEQ 512
#define UNITS 256
#define RU 512

__device__ __forceinline__ float sigmoidf_(float v) {
    return 1.0f / (1.0f + __expf(-v));
}
__device__ __forceinline__ float tanhf_(float v) {
    float e = __expf(2.0f * v);
    return 1.0f - 2.0f / (e + 1.0f);
}

// ---------------------------------------------------------------------------
// Encoder: fwd+bwd masked LSTM. 128 blocks: 0..63 fwd (batch pairs), 64..127
// bwd. Each block owns 2 batch elements, runs all 512 steps. x/mask staged in
// LDS once; Wk/bias in registers; Wr double-buffer-prefetched in registers.
// ---------------------------------------------------------------------------
__global__ __launch_bounds__(1024)
void encoder_kernel(const float* __restrict__ x,
                    const float* __restrict__ Wf_k, const float* __restrict__ Wf_r,
                    const float* __restrict__ bf,
                    const float* __restrict__ Wb_k, const float* __restrict__ Wb_r,
                    const float* __restrict__ bb,
                    float* __restrict__ enc)
{
    const int bid  = blockIdx.x;
    const int dir  = bid >> 6;          // 0 = fwd, 1 = bwd
    const int pair = bid & 63;
    const int b0 = pair * 2, b1 = b0 + 1;
    const float* __restrict__ Wk   = dir ? Wb_k : Wf_k;
    const float* __restrict__ Wr   = dir ? Wb_r : Wf_r;
    const float* __restrict__ bias = dir ? bb : bf;
    const int off = dir ? UNITS : 0;
    const int tid = threadIdx.x;

    __shared__ float xAll[2][CCH][SEQ];      // 20 KB
    __shared__ int   mAll[2][SEQ];           // 4 KB
    __shared__ float __align__(16) hL[2][UNITS];
    __shared__ float cL[2][UNITS];
    __shared__ float zL[2][1024];

    // one-time staging of x (feature 0) and mask (feature 2 of channel 0)
    for (int i = tid; i < 2 * CCH * SEQ; i += 1024) {
        int g = i / (CCH * SEQ), r = i % (CCH * SEQ);
        int c = r / SEQ, t = r % SEQ;
        int b = g ? b1 : b0;
        xAll[g][c][t] = x[((size_t)(b * CCH + c) * SEQ + t) * 3];
    }
    for (int i = tid; i < 2 * SEQ; i += 1024) {
        int g = i >> 9, t = i & (SEQ - 1);
        int b = g ? b1 : b0;
        mAll[g][t] = (x[((size_t)(b * CCH) * SEQ + t) * 3 + 2] != 0.0f);
    }
    if (tid < 2 * UNITS) {
        ((float*)hL)[tid] = 0.0f;
        ((float*)cL)[tid] = 0.0f;
    }
    const float bias_r = bias[tid];
    float wk_r[CCH];
    #pragma unroll
    for (int c = 0; c < CCH; ++c) wk_r[c] = Wk[c * 1024 + tid];
    __syncthreads();

    const float* __restrict__ wrp = Wr + tid;
    float wA[8], wB[8];

    #define ENC_LOAD(W, K0) { _Pragma("unroll") for (int i_ = 0; i_ < 8; ++i_) \
        W[i_] = wrp[(size_t)((K0) + i_) * 1024]; }
    #define ENC_COMP(W, K0) { \
        float4 a0_ = *(const float4*)&hL[0][(K0)]; \
        float4 a1_ = *(const float4*)&hL[0][(K0) + 4]; \
        float4 b0_ = *(const float4*)&hL[1][(K0)]; \
        float4 b1_ = *(const float4*)&hL[1][(K0) + 4]; \
        z0 = fmaf(a0_.x, W[0], z0); z1 = fmaf(b0_.x, W[0], z1); \
        z0 = fmaf(a0_.y, W[1], z0); z1 = fmaf(b0_.y, W[1], z1); \
        z0 = fmaf(a0_.z, W[2], z0); z1 = fmaf(b0_.z, W[2], z1); \
        z0 = fmaf(a0_.w, W[3], z0); z1 = fmaf(b0_.w, W[3], z1); \
        z0 = fmaf(a1_.x, W[4], z0); z1 = fmaf(b1_.x, W[4], z1); \
        z0 = fmaf(a1_.y, W[5], z0); z1 = fmaf(b1_.y, W[5], z1); \
        z0 = fmaf(a1_.z, W[6], z0); z1 = fmaf(b1_.z, W[6], z1); \
        z0 = fmaf(a1_.w, W[7], z0); z1 = fmaf(b1_.w, W[7], z1); }

    ENC_LOAD(wA, 0)

    for (int t = 0; t < SEQ; ++t) {
        const int ts = dir ? (SEQ - 1 - t) : t;
        float z0 = bias_r, z1 = bias_r;
        #pragma unroll
        for (int c = 0; c < CCH; ++c) {
            z0 = fmaf(xAll[0][c][ts], wk_r[c], z0);
            z1 = fmaf(xAll[1][c][ts], wk_r[c], z1);
        }
        for (int k0 = 0; k0 < UNITS; k0 += 16) {
            ENC_LOAD(wB, k0 + 8)
            ENC_COMP(wA, k0)
            ENC_LOAD(wA, (k0 + 16) & (UNITS - 1))   // wraps -> next step's prefetch
            ENC_COMP(wB, k0 + 8)
        }
        zL[0][tid] = z0;
        zL[1][tid] = z1;
        __syncthreads();
        if (tid < 2 * UNITS) {
            int g = tid >> 8, uu = tid & (UNITS - 1);
            float iv = zL[g][uu];
            float fv = zL[g][uu + UNITS];
            float gv = zL[g][uu + 2 * UNITS];
            float ov = zL[g][uu + 3 * UNITS];
            float cn = sigmoidf_(fv) * cL[g][uu] + sigmoidf_(iv) * tanhf_(gv);
            float hn = sigmoidf_(ov) * tanhf_(cn);
            float h2, c2;
            if (mAll[g][ts]) { h2 = hn; c2 = cn; }
            else             { h2 = hL[g][uu]; c2 = cL[g][uu]; }
            hL[g][uu] = h2;
            cL[g][uu] = c2;
            int b = g ? b1 : b0;
            enc[((size_t)b * SEQ + ts) * RU + off + uu] = h2;
        }
        __syncthreads();
    }
    #undef ENC_LOAD
    #undef ENC_COMP
}

// ---------------------------------------------------------------------------
// Attention precompute (alpha is constant over decoder time since the
// per-batch scalar shift cancels in softmax). One block per batch.
// ---------------------------------------------------------------------------
__global__ __launch_bounds__(256)
void attn_kernel(const float* __restrict__ enc,
                 const float* __restrict__ W_attn, const float* __restrict__ b_attn,
                 const float* __restrict__ W_dense, const float* __restrict__ b_dense,
                 const float* __restrict__ x,
                 float* __restrict__ attn_ws, float* __restrict__ hidden_ws,
                 float* __restrict__ xbuf, float* __restrict__ xconst)
{
    const int b = blockIdx.x;
    const int tid = threadIdx.x;
    const int lane = tid & 63;
    const int wv = tid >> 6;

    __shared__ float WeL[RU];
    __shared__ float scoresL[SEQ];
    __shared__ float red[256];
    __shared__ float attnL[RU];

    WeL[tid]       = W_attn[CCH + tid];
    WeL[tid + 256] = W_attn[CCH + tid + 256];
    __syncthreads();

    const float* __restrict__ encb = enc + (size_t)b * SEQ * RU;
    const float batt = b_attn[0];

    for (int s = wv; s < SEQ; s += 4) {
        const float* row = encb + (size_t)s * RU;
        float p = 0.0f;
        #pragma unroll
        for (int i = 0; i < 8; ++i) {
            int d = lane * 8 + i;
            p = fmaf(row[d], WeL[d], p);
        }
        #pragma unroll
        for (int o = 32; o; o >>= 1) p += __shfl_xor(p, o);
        if (lane == 0) scoresL[s] = p + batt;
    }
    __syncthreads();

    float m = fmaxf(scoresL[tid], scoresL[tid + 256]);
    red[tid] = m;
    __syncthreads();
    for (int st = 128; st; st >>= 1) {
        if (tid < st) red[tid] = fmaxf(red[tid], red[tid + st]);
        __syncthreads();
    }
    const float mx = red[0];
    __syncthreads();
    float e0 = __expf(scoresL[tid] - mx);
    float e1 = __expf(scoresL[tid + 256] - mx);
    red[tid] = e0 + e1;
    __syncthreads();
    for (int st = 128; st; st >>= 1) {
        if (tid < st) red[tid] += red[tid + st];
        __syncthreads();
    }
    const float sinv = 1.0f / red[0];
    __syncthreads();
    scoresL[tid]       = e0 * sinv;
    scoresL[tid + 256] = e1 * sinv;
    __syncthreads();

    float a0 = 0.0f, a1 = 0.0f;
    for (int s = 0; s < SEQ; ++s) {
        float al = scoresL[s];
        a0 = fmaf(al, encb[(size_t)s * RU + tid], a0);
        a1 = fmaf(al, encb[(size_t)s * RU + tid + 256], a1);
    }
    attn_ws[(size_t)b * RU + tid]       = a0;
    attn_ws[(size_t)b * RU + tid + 256] = a1;
    attnL[tid] = a0;
    attnL[tid + 256] = a1;
    hidden_ws[(size_t)b * RU + tid]       = encb[(size_t)(SEQ - 1) * RU + tid];
    hidden_ws[(size_t)b * RU + tid + 256] = encb[(size_t)(SEQ - 1) * RU + tid + 256];
    if (tid < CCH) xbuf[b * CCH + tid] = x[((size_t)(b * CCH + tid) * SEQ + 0) * 3];
    __syncthreads();

    if (tid < CCH) {
        float acc = b_dense[tid];
        for (int d = 0; d < RU; ++d)
            acc = fmaf(attnL[d], W_dense[(RU + d) * CCH + tid], acc);
        xconst[b * CCH + tid] = acc;
    }
}

// ---------------------------------------------------------------------------
// Decoder: 511 steps; attn (cell input) constant. 64 blocks x 2 batches.
// Thread owns adjacent j-pair (2*tid, 2*tid+1): float2 weight loads,
// register double-buffer prefetch with wraparound across steps.
// ---------------------------------------------------------------------------
__global__ __launch_bounds__(1024)
void decoder_kernel(const float* __restrict__ Wd_k, const float* __restrict__ Wd_r,
                    const float* __restrict__ bd,
                    const float* __restrict__ W_dense,
                    const float* __restrict__ attn_ws, const float* __restrict__ hidden_ws,
                    const float* __restrict__ xbuf, const float* __restrict__ xconst,
                    float* __restrict__ out)
{
    const int gblk = blockIdx.x;
    const int b0 = gblk * 2, b1 = b0 + 1;
    const int tid = threadIdx.x;
    const int lane = tid & 63;
    const int wv = tid >> 6;

    __shared__ float __align__(16) hL[2][RU];      // 4 KB
    __shared__ float zL[2][4 * RU];                // 16 KB
    __shared__ float WdL[RU * CCH];                // 10 KB
    __shared__ float xL[2][CCH];
    __shared__ float xcL[2][CCH];

    if (tid < RU) {
        hL[0][tid] = hidden_ws[(size_t)b0 * RU + tid];
        hL[1][tid] = hidden_ws[(size_t)b1 * RU + tid];
    }
    for (int i = tid; i < RU * CCH; i += 1024) WdL[i] = W_dense[i];
    if (tid < 2 * CCH) {
        int g = tid / CCH, c = tid % CCH;
        int b = g ? b1 : b0;
        xL[g][c]  = xbuf[b * CCH + c];
        xcL[g][c] = xconst[b * CCH + c];
    }
    // per-thread register-cached constants
    const int j2 = 2 * tid;
    const float2 bdv = *(const float2*)&bd[j2];
    float2 wkv[CCH];
    #pragma unroll
    for (int c = 0; c < CCH; ++c) wkv[c] = *(const float2*)&Wd_k[c * 2048 + j2];
    const int cg = tid >> 9, cu = tid & (RU - 1);
    const float att = attn_ws[(size_t)(cg ? b1 : b0) * RU + cu];
    __syncthreads();

    const float* __restrict__ wr2 = Wd_r + j2;
    float2 wA[8], wB[8];

    #define DEC_LOAD(W, K0) { _Pragma("unroll") for (int i_ = 0; i_ < 8; ++i_) \
        W[i_] = *(const float2*)&wr2[(size_t)((K0) + i_) * 2048]; }
    #define DEC_FMA(HA, HB, WW) { \
        za0 = fmaf(HA, WW.x, za0); za1 = fmaf(HA, WW.y, za1); \
        zb0 = fmaf(HB, WW.x, zb0); zb1 = fmaf(HB, WW.y, zb1); }
    #define DEC_COMP(W, K0) { \
        float4 a0_ = *(const float4*)&hL[0][(K0)]; \
        float4 a1_ = *(const float4*)&hL[0][(K0) + 4]; \
        float4 b0_ = *(const float4*)&hL[1][(K0)]; \
        float4 b1_ = *(const float4*)&hL[1][(K0) + 4]; \
        DEC_FMA(a0_.x, b0_.x, W[0]) \
        DEC_FMA(a0_.y, b0_.y, W[1]) \
        DEC_FMA(a0_.z, b0_.z, W[2]) \
        DEC_FMA(a0_.w, b0_.w, W[3]) \
        DEC_FMA(a1_.x, b1_.x, W[4]) \
        DEC_FMA(a1_.y, b1_.y, W[5]) \
        DEC_FMA(a1_.z, b1_.z, W[6]) \
        DEC_FMA(a1_.w, b1_.w, W[7]) }

    DEC_LOAD(wA, 0)

    for (int t = 0; t < SEQ - 1; ++t) {
        float za0 = bdv.x, za1 = bdv.y, zb0 = bdv.x, zb1 = bdv.y;
        #pragma unroll
        for (int c = 0; c < CCH; ++c) {
            float xa = xL[0][c], xb = xL[1][c];
            za0 = fmaf(xa, wkv[c].x, za0); za1 = fmaf(xa, wkv[c].y, za1);
            zb0 = fmaf(xb, wkv[c].x, zb0); zb1 = fmaf(xb, wkv[c].y, zb1);
        }
        for (int k0 = 0; k0 < RU; k0 += 16) {
            DEC_LOAD(wB, k0 + 8)
            DEC_COMP(wA, k0)
            DEC_LOAD(wA, (k0 + 16) & (RU - 1))   // wraps -> next step's group 0
            DEC_COMP(wB, k0 + 8)
        }
        *(float2*)&zL[0][j2] = make_float2(za0, za1);
        *(float2*)&zL[1][j2] = make_float2(zb0, zb1);
        __syncthreads();
        // cell update: 1024 threads = 2 batches x 512 units
        {
            float iv = zL[cg][cu];
            float fv = zL[cg][cu + RU];
            float gv = zL[cg][cu + 2 * RU];
            float ov = zL[cg][cu + 3 * RU];
            float cn = sigmoidf_(fv) * att + sigmoidf_(iv) * tanhf_(gv);
            hL[cg][cu] = sigmoidf_(ov) * tanhf_(cn);
        }
        __syncthreads();
        // x_new = xconst + h_new . W_dense[:RU]  (10 wave-reductions from LDS)
        if (wv < 2 * CCH) {
            int g = wv / CCH, c = wv % CCH;
            float p = 0.0f;
            #pragma unroll
            for (int it = 0; it < RU / 64; ++it) {
                int u = lane + it * 64;
                p = fmaf(hL[g][u], WdL[u * CCH + c], p);
            }
            #pragma unroll
            for (int o = 32; o; o >>= 1) p += __shfl_xor(p, o);
            if (lane == 0) {
                float xn = p + xcL[g][c];
                xL[g][c] = xn;
                out[(size_t)((g ? b1 : b0) * CCH + c) * (SEQ - 1) + t] = xn;
            }
        }
        __syncthreads();
    }
    #undef DEC_LOAD
    #undef DEC_FMA
    #undef DEC_COMP
}

// ---------------------------------------------------------------------------
extern "C" void kernel_launch(void* const* d_in, const int* in_sizes, int n_in,
                              void* d_out, int out_size, void* d_ws, size_t ws_size,
                              hipStream_t stream)
{
    const float* x       = (const float*)d_in[0];
    const float* Wf_k    = (const float*)d_in[1];
    const float* Wf_r    = (const float*)d_in[2];
    const float* bf      = (const float*)d_in[3];
    const float* Wb_k    = (const float*)d_in[4];
    const float* Wb_r    = (const float*)d_in[5];
    const float* bb      = (const float*)d_in[6];
    const float* Wd_k    = (const float*)d_in[7];
    const float* Wd_r    = (const float*)d_in[8];
    const float* bd      = (const float*)d_in[9];
    const float* W_attn  = (const float*)d_in[10];
    const float* b_attn  = (const float*)d_in[11];
    const float* W_dense = (const float*)d_in[12];
    const float* b_dense = (const float*)d_in[13];
    float* out = (float*)d_out;

    float* ws     = (float*)d_ws;
    float* enc    = ws;                                   // B*S*RU floats
    float* attn   = ws + (size_t)BATCH * SEQ * RU;        // B*RU
    float* hidden = attn + (size_t)BATCH * RU;            // B*RU
    float* xbuf   = hidden + (size_t)BATCH * RU;          // B*C
    float* xconst = xbuf + (size_t)BATCH * CCH;           // B*C

    encoder_kernel<<<128, 1024, 0, stream>>>(x, Wf_k, Wf_r, bf, Wb_k, Wb_r, bb, enc);
    attn_kernel<<<BATCH, 256, 0, stream>>>(enc, W_attn, b_attn, W_dense, b_dense, x,
                                           attn, hidden, xbuf, xconst);
    decoder_kernel<<<64, 1024, 0, stream>>>(Wd_k, Wd_r, bd, W_dense,
                                            attn, hidden, xbuf, xconst, out);
}

// Round 3
// 20875.739 us; speedup vs baseline: 1.6889x; 1.6889x over previous
//
#include <hip/hip_runtime.h>
#include <math.h>

#define BATCH 128
#define CCH 5
#define SEQ 512
#define UNITS 256
#define RU 512

#define ENC_N 33554432   // BATCH*SEQ*RU floats

__device__ __forceinline__ float sigmoidf_(float v) {
    return 1.0f / (1.0f + __expf(-v));
}
__device__ __forceinline__ float aloadf(const float* p) {
    return __hip_atomic_load(p, __ATOMIC_RELAXED, __HIP_MEMORY_SCOPE_AGENT);
}
__device__ __forceinline__ void astoref(float* p, float v) {
    __hip_atomic_store(p, v, __ATOMIC_RELAXED, __HIP_MEMORY_SCOPE_AGENT);
}

// 8-row FMA block: W = float2[8] weights (2 cols), h from LDS hL[g][rb+R0..+7]
#define COMP8(W, R0) { \
    const float4 h0a = *(const float4*)&hL[0][rb + (R0)]; \
    const float4 h0b = *(const float4*)&hL[0][rb + (R0) + 4]; \
    const float4 h1a = *(const float4*)&hL[1][rb + (R0)]; \
    const float4 h1b = *(const float4*)&hL[1][rb + (R0) + 4]; \
    za0=fmaf(h0a.x,W[0].x,za0); za1=fmaf(h0a.x,W[0].y,za1); zb0=fmaf(h1a.x,W[0].x,zb0); zb1=fmaf(h1a.x,W[0].y,zb1); \
    za0=fmaf(h0a.y,W[1].x,za0); za1=fmaf(h0a.y,W[1].y,za1); zb0=fmaf(h1a.y,W[1].x,zb0); zb1=fmaf(h1a.y,W[1].y,zb1); \
    za0=fmaf(h0a.z,W[2].x,za0); za1=fmaf(h0a.z,W[2].y,za1); zb0=fmaf(h1a.z,W[2].x,zb0); zb1=fmaf(h1a.z,W[2].y,zb1); \
    za0=fmaf(h0a.w,W[3].x,za0); za1=fmaf(h0a.w,W[3].y,za1); zb0=fmaf(h1a.w,W[3].x,zb0); zb1=fmaf(h1a.w,W[3].y,zb1); \
    za0=fmaf(h0b.x,W[4].x,za0); za1=fmaf(h0b.x,W[4].y,za1); zb0=fmaf(h1b.x,W[4].x,zb0); zb1=fmaf(h1b.x,W[4].y,zb1); \
    za0=fmaf(h0b.y,W[5].x,za0); za1=fmaf(h0b.y,W[5].y,za1); zb0=fmaf(h1b.y,W[5].x,zb0); zb1=fmaf(h1b.y,W[5].y,zb1); \
    za0=fmaf(h0b.z,W[6].x,za0); za1=fmaf(h0b.z,W[6].y,za1); zb0=fmaf(h1b.z,W[6].x,zb0); zb1=fmaf(h1b.z,W[6].y,zb1); \
    za0=fmaf(h0b.w,W[7].x,za0); za1=fmaf(h0b.w,W[7].y,za1); zb0=fmaf(h1b.w,W[7].x,zb0); zb1=fmaf(h1b.w,W[7].y,zb1); }

#define WLOAD(W, R0, STRIDE) { _Pragma("unroll") for (int i_ = 0; i_ < 8; ++i_) \
    W[i_] = *(const float2*)(wp + (size_t)((R0) + i_) * (STRIDE)); }

// ---------------------------------------------------------------------------
// Encoder: 256 blocks = dir(2) x pair(64) x slice(2). Each block owns 128
// units (512 of 1024 z-cols) for 2 batches; per-step h exchange with the
// partner slice via L3 (agent-scope atomics + monotone counter).
// ---------------------------------------------------------------------------
__global__ __launch_bounds__(1024)
void encoder_kernel(const float* __restrict__ x,
                    const float* __restrict__ Wf_k, const float* __restrict__ Wf_r,
                    const float* __restrict__ bf,
                    const float* __restrict__ Wb_k, const float* __restrict__ Wb_r,
                    const float* __restrict__ bb,
                    float* __restrict__ enc, float* __restrict__ h_ex,
                    int* __restrict__ cnt)
{
    const int bid   = blockIdx.x;
    const int dir   = bid >> 7;
    const int pair  = (bid >> 1) & 63;
    const int slice = bid & 1;
    const int gidx  = dir * 64 + pair;
    const int b0 = pair * 2, b1 = b0 + 1;
    const float* __restrict__ Wk   = dir ? Wb_k : Wf_k;
    const float* __restrict__ Wr   = dir ? Wb_r : Wf_r;
    const float* __restrict__ bias = dir ? bb : bf;
    const int tid = threadIdx.x;
    const int rg  = tid >> 8;          // 0..3 row-groups of 64
    const int cs  = tid & 255;         // col-slot: 2 adjacent cols
    const int jj0 = cs * 2;
    const int gate = jj0 >> 7;
    const int j   = gate * 256 + slice * 128 + (jj0 & 127);
    const int rb  = rg * 64;

    __shared__ float xAll[2][CCH][SEQ];            // 20 KB
    __shared__ unsigned char mAll[2][SEQ];         // 1 KB
    __shared__ float __align__(16) hL[2][UNITS];   // 2 KB
    __shared__ float cL[2][128];                   // 1 KB
    __shared__ float __align__(8) zp[4][2][512];   // 16 KB

    for (int i = tid; i < 2 * CCH * SEQ; i += 1024) {
        int g = i / (CCH * SEQ), r = i % (CCH * SEQ);
        int c = r / SEQ, t = r % SEQ;
        xAll[g][c][t] = x[((size_t)((g ? b1 : b0) * CCH + c) * SEQ + t) * 3];
    }
    for (int i = tid; i < 2 * SEQ; i += 1024) {
        int g = i >> 9, t = i & (SEQ - 1);
        mAll[g][t] = (x[((size_t)((g ? b1 : b0) * CCH) * SEQ + t) * 3 + 2] != 0.0f) ? 1 : 0;
    }
    if (tid < 512) hL[tid >> 8][tid & 255] = 0.0f;
    if (tid < 256) cL[tid >> 7][tid & 127] = 0.0f;

    const float2 bias2 = *(const float2*)&bias[j];
    float2 wk2[CCH];
    #pragma unroll
    for (int c = 0; c < CCH; ++c) wk2[c] = *(const float2*)&Wk[c * 1024 + j];
    __syncthreads();

    const float* __restrict__ wp = Wr + (size_t)rb * 1024 + j;
    float2 wA[8], wB[8];
    WLOAD(wA, 0, 1024)

    for (int t = 0; t < SEQ; ++t) {
        const int ts = dir ? (SEQ - 1 - t) : t;
        if (t > 0) {
            if (tid == 0) {
                const int target = 2 * t;
                long guard = 0;
                while (__hip_atomic_load(&cnt[gidx], __ATOMIC_RELAXED,
                                         __HIP_MEMORY_SCOPE_AGENT) < target &&
                       guard < (1L << 24)) { __builtin_amdgcn_s_sleep(2); ++guard; }
            }
            __syncthreads();
            if (tid < 512) {
                int g = tid >> 8, uu = tid & 255;
                hL[g][uu] = aloadf(&h_ex[((size_t)gidx * 2 + ((t - 1) & 1)) * 512 + g * 256 + uu]);
            }
            __syncthreads();
        }
        float za0, za1, zb0, zb1;
        if (rg == 0) {
            za0 = bias2.x; za1 = bias2.y; zb0 = bias2.x; zb1 = bias2.y;
            #pragma unroll
            for (int c = 0; c < CCH; ++c) {
                float xa = xAll[0][c][ts], xb = xAll[1][c][ts];
                za0 = fmaf(xa, wk2[c].x, za0); za1 = fmaf(xa, wk2[c].y, za1);
                zb0 = fmaf(xb, wk2[c].x, zb0); zb1 = fmaf(xb, wk2[c].y, zb1);
            }
        } else { za0 = za1 = zb0 = zb1 = 0.0f; }

        for (int r = 0; r < 64; r += 16) {
            WLOAD(wB, r + 8, 1024)
            COMP8(wA, r)
            WLOAD(wA, (r + 16) & 63, 1024)
            COMP8(wB, r + 8)
        }
        *(float2*)&zp[rg][0][jj0] = make_float2(za0, za1);
        *(float2*)&zp[rg][1][jj0] = make_float2(zb0, zb1);
        __syncthreads();

        if (tid < 256) {
            int g = tid >> 7, u = tid & 127;
            float zi = zp[0][g][u]       + zp[1][g][u]       + zp[2][g][u]       + zp[3][g][u];
            float zf = zp[0][g][128 + u] + zp[1][g][128 + u] + zp[2][g][128 + u] + zp[3][g][128 + u];
            float zg = zp[0][g][256 + u] + zp[1][g][256 + u] + zp[2][g][256 + u] + zp[3][g][256 + u];
            float zo = zp[0][g][384 + u] + zp[1][g][384 + u] + zp[2][g][384 + u] + zp[3][g][384 + u];
            float cn = sigmoidf_(zf) * cL[g][u] + sigmoidf_(zi) * tanhf(zg);
            float hn = sigmoidf_(zo) * tanhf(cn);
            if (!mAll[g][ts]) { hn = hL[g][slice * 128 + u]; cn = cL[g][u]; }
            cL[g][u] = cn;
            hL[g][slice * 128 + u] = hn;
            astoref(&h_ex[((size_t)gidx * 2 + (t & 1)) * 512 + g * 256 + slice * 128 + u], hn);
            enc[((size_t)(g ? b1 : b0) * SEQ + ts) * RU + dir * 256 + slice * 128 + u] = hn;
        }
        __syncthreads();
        if (tid == 0)
            __hip_atomic_fetch_add(&cnt[gidx], 1, __ATOMIC_RELAXED, __HIP_MEMORY_SCOPE_AGENT);
    }
}

// ---------------------------------------------------------------------------
// Attention precompute (alpha constant over decoder time). One block/batch.
// ---------------------------------------------------------------------------
__global__ __launch_bounds__(256)
void attn_kernel(const float* __restrict__ enc,
                 const float* __restrict__ W_attn, const float* __restrict__ b_attn,
                 const float* __restrict__ W_dense, const float* __restrict__ b_dense,
                 const float* __restrict__ x,
                 float* __restrict__ attn_ws, float* __restrict__ hidden_ws,
                 float* __restrict__ xbuf, float* __restrict__ xconst)
{
    const int b = blockIdx.x;
    const int tid = threadIdx.x;
    const int lane = tid & 63;
    const int wv = tid >> 6;

    __shared__ float WeL[RU];
    __shared__ float scoresL[SEQ];
    __shared__ float red[256];
    __shared__ float attnL[RU];

    WeL[tid]       = W_attn[CCH + tid];
    WeL[tid + 256] = W_attn[CCH + tid + 256];
    __syncthreads();

    const float* __restrict__ encb = enc + (size_t)b * SEQ * RU;
    const float batt = b_attn[0];

    for (int s = wv; s < SEQ; s += 4) {
        const float* row = encb + (size_t)s * RU;
        float p = 0.0f;
        #pragma unroll
        for (int i = 0; i < 8; ++i) {
            int d = lane * 8 + i;
            p = fmaf(row[d], WeL[d], p);
        }
        #pragma unroll
        for (int o = 32; o; o >>= 1) p += __shfl_xor(p, o);
        if (lane == 0) scoresL[s] = p + batt;
    }
    __syncthreads();

    float m = fmaxf(scoresL[tid], scoresL[tid + 256]);
    red[tid] = m;
    __syncthreads();
    for (int st = 128; st; st >>= 1) {
        if (tid < st) red[tid] = fmaxf(red[tid], red[tid + st]);
        __syncthreads();
    }
    const float mx = red[0];
    __syncthreads();
    float e0 = __expf(scoresL[tid] - mx);
    float e1 = __expf(scoresL[tid + 256] - mx);
    red[tid] = e0 + e1;
    __syncthreads();
    for (int st = 128; st; st >>= 1) {
        if (tid < st) red[tid] += red[tid + st];
        __syncthreads();
    }
    const float sinv = 1.0f / red[0];
    __syncthreads();
    scoresL[tid]       = e0 * sinv;
    scoresL[tid + 256] = e1 * sinv;
    __syncthreads();

    float a0 = 0.0f, a1 = 0.0f;
    for (int s = 0; s < SEQ; ++s) {
        float al = scoresL[s];
        a0 = fmaf(al, encb[(size_t)s * RU + tid], a0);
        a1 = fmaf(al, encb[(size_t)s * RU + tid + 256], a1);
    }
    attn_ws[(size_t)b * RU + tid]       = a0;
    attn_ws[(size_t)b * RU + tid + 256] = a1;
    attnL[tid] = a0;
    attnL[tid + 256] = a1;
    hidden_ws[(size_t)b * RU + tid]       = encb[(size_t)(SEQ - 1) * RU + tid];
    hidden_ws[(size_t)b * RU + tid + 256] = encb[(size_t)(SEQ - 1) * RU + tid + 256];
    if (tid < CCH) xbuf[b * CCH + tid] = x[((size_t)(b * CCH + tid) * SEQ + 0) * 3];
    __syncthreads();

    if (tid < CCH) {
        float acc = b_dense[tid];
        for (int d = 0; d < RU; ++d)
            acc = fmaf(attnL[d], W_dense[(RU + d) * CCH + tid], acc);
        xconst[b * CCH + tid] = acc;
    }
}

// ---------------------------------------------------------------------------
// Decoder: 256 blocks = pair(64) x slice(4). Each block owns 128 units
// (512 of 2048 z-cols) for 2 batches; per-step h/dense-partial exchange
// among the 4 slices via L3 (agent atomics + monotone counter).
// ---------------------------------------------------------------------------
__global__ __launch_bounds__(1024)
void decoder_kernel(const float* __restrict__ Wd_k, const float* __restrict__ Wd_r,
                    const float* __restrict__ bd,
                    const float* __restrict__ W_dense,
                    const float* __restrict__ attn_ws, const float* __restrict__ hidden_ws,
                    const float* __restrict__ xbuf, const float* __restrict__ xconst,
                    float* __restrict__ h_ex, float* __restrict__ xpart,
                    int* __restrict__ cnt, float* __restrict__ out)
{
    const int bid   = blockIdx.x;
    const int pair  = bid >> 2;
    const int slice = bid & 3;
    const int b0 = pair * 2, b1 = b0 + 1;
    const int tid = threadIdx.x;
    const int lane = tid & 63;
    const int wv = tid >> 6;
    const int rg  = tid >> 8;          // 0..3 row-groups of 128
    const int cs  = tid & 255;
    const int jj0 = cs * 2;
    const int gate = jj0 >> 7;
    const int j   = gate * 512 + slice * 128 + (jj0 & 127);
    const int rb  = rg * 128;

    __shared__ float __align__(16) hL[2][RU];      // 4 KB
    __shared__ float attL[2][128];                 // 1 KB
    __shared__ float __align__(8) zp[4][2][512];   // 16 KB
    __shared__ float WdL[128 * CCH];               // 2.5 KB
    __shared__ float xL[2][CCH], xcL[2][CCH];

    {
        int g = tid >> 9, uu = tid & 511;
        hL[g][uu] = hidden_ws[(size_t)(g ? b1 : b0) * RU + uu];
    }
    if (tid < 256) {
        int g = tid >> 7, u = tid & 127;
        attL[g][u] = attn_ws[(size_t)(g ? b1 : b0) * RU + slice * 128 + u];
    }
    if (tid < 128 * CCH)
        WdL[tid] = W_dense[(slice * 128 + tid / CCH) * CCH + (tid % CCH)];
    if (tid < 2 * CCH) {
        int g = tid / CCH, c = tid % CCH;
        xL[g][c]  = xbuf[(g ? b1 : b0) * CCH + c];
        xcL[g][c] = xconst[(g ? b1 : b0) * CCH + c];
    }
    const float2 bd2 = *(const float2*)&bd[j];
    float2 wk2[CCH];
    #pragma unroll
    for (int c = 0; c < CCH; ++c) wk2[c] = *(const float2*)&Wd_k[c * 2048 + j];
    __syncthreads();

    const float* __restrict__ wp = Wd_r + (size_t)rb * 2048 + j;
    float2 wA[8], wB[8];
    WLOAD(wA, 0, 2048)

    for (int t = 0; t < SEQ - 1; ++t) {
        if (t > 0) {
            if (tid == 0) {
                const int target = 4 * t;
                long guard = 0;
                while (__hip_atomic_load(&cnt[pair], __ATOMIC_RELAXED,
                                         __HIP_MEMORY_SCOPE_AGENT) < target &&
                       guard < (1L << 24)) { __builtin_amdgcn_s_sleep(2); ++guard; }
            }
            __syncthreads();
            {
                int g = tid >> 9, uu = tid & 511;
                hL[g][uu] = aloadf(&h_ex[((size_t)pair * 2 + ((t - 1) & 1)) * 1024 + g * 512 + uu]);
            }
            if (tid < 2 * CCH) {
                int g = tid / CCH, c = tid % CCH;
                float s = xcL[g][c];
                #pragma unroll
                for (int sl = 0; sl < 4; ++sl)
                    s += aloadf(&xpart[(((size_t)pair * 2 + ((t - 1) & 1)) * 4 + sl) * 10 + g * CCH + c]);
                xL[g][c] = s;
                if (slice == 0)
                    out[((size_t)((g ? b1 : b0) * CCH + c)) * (SEQ - 1) + (t - 1)] = s;
            }
            __syncthreads();
        }
        float za0, za1, zb0, zb1;
        if (rg == 0) {
            za0 = bd2.x; za1 = bd2.y; zb0 = bd2.x; zb1 = bd2.y;
            #pragma unroll
            for (int c = 0; c < CCH; ++c) {
                float xa = xL[0][c], xb = xL[1][c];
                za0 = fmaf(xa, wk2[c].x, za0); za1 = fmaf(xa, wk2[c].y, za1);
                zb0 = fmaf(xb, wk2[c].x, zb0); zb1 = fmaf(xb, wk2[c].y, zb1);
            }
        } else { za0 = za1 = zb0 = zb1 = 0.0f; }

        for (int r = 0; r < 128; r += 16) {
            WLOAD(wB, r + 8, 2048)
            COMP8(wA, r)
            WLOAD(wA, (r + 16) & 127, 2048)
            COMP8(wB, r + 8)
        }
        *(float2*)&zp[rg][0][jj0] = make_float2(za0, za1);
        *(float2*)&zp[rg][1][jj0] = make_float2(zb0, zb1);
        __syncthreads();

        if (tid < 256) {
            int g = tid >> 7, u = tid & 127;
            float zi = zp[0][g][u]       + zp[1][g][u]       + zp[2][g][u]       + zp[3][g][u];
            float zf = zp[0][g][128 + u] + zp[1][g][128 + u] + zp[2][g][128 + u] + zp[3][g][128 + u];
            float zg = zp[0][g][256 + u] + zp[1][g][256 + u] + zp[2][g][256 + u] + zp[3][g][256 + u];
            float zo = zp[0][g][384 + u] + zp[1][g][384 + u] + zp[2][g][384 + u] + zp[3][g][384 + u];
            float cn = sigmoidf_(zf) * attL[g][u] + sigmoidf_(zi) * tanhf(zg);
            float hn = sigmoidf_(zo) * tanhf(cn);
            hL[g][slice * 128 + u] = hn;
            astoref(&h_ex[((size_t)pair * 2 + (t & 1)) * 1024 + g * 512 + slice * 128 + u], hn);
        }
        __syncthreads();

        if (wv < 10) {
            int g = wv / 5, c = wv % 5;
            float p = fmaf(hL[g][slice * 128 + lane],      WdL[lane * CCH + c],
                     fmaf(hL[g][slice * 128 + 64 + lane],  WdL[(64 + lane) * CCH + c], 0.0f));
            #pragma unroll
            for (int o = 32; o; o >>= 1) p += __shfl_xor(p, o);
            if (lane == 0)
                astoref(&xpart[(((size_t)pair * 2 + (t & 1)) * 4 + slice) * 10 + g * CCH + c], p);
        }
        __syncthreads();
        if (tid == 0)
            __hip_atomic_fetch_add(&cnt[pair], 1, __ATOMIC_RELAXED, __HIP_MEMORY_SCOPE_AGENT);
    }

    // epilogue: write out[t=510]
    if (slice == 0) {
        if (tid == 0) {
            const int target = 4 * (SEQ - 1);
            long guard = 0;
            while (__hip_atomic_load(&cnt[pair], __ATOMIC_RELAXED,
                                     __HIP_MEMORY_SCOPE_AGENT) < target &&
                   guard < (1L << 24)) { __builtin_amdgcn_s_sleep(2); ++guard; }
        }
        __syncthreads();
        if (tid < 2 * CCH) {
            int g = tid / CCH, c = tid % CCH;
            float s = xcL[g][c];
            #pragma unroll
            for (int sl = 0; sl < 4; ++sl)
                s += aloadf(&xpart[(((size_t)pair * 2 + ((SEQ - 2) & 1)) * 4 + sl) * 10 + g * CCH + c]);
            out[((size_t)((g ? b1 : b0) * CCH + c)) * (SEQ - 1) + (SEQ - 2)] = s;
        }
    }
}

// ---------------------------------------------------------------------------
extern "C" void kernel_launch(void* const* d_in, const int* in_sizes, int n_in,
                              void* d_out, int out_size, void* d_ws, size_t ws_size,
                              hipStream_t stream)
{
    const float* x       = (const float*)d_in[0];
    const float* Wf_k    = (const float*)d_in[1];
    const float* Wf_r    = (const float*)d_in[2];
    const float* bf      = (const float*)d_in[3];
    const float* Wb_k    = (const float*)d_in[4];
    const float* Wb_r    = (const float*)d_in[5];
    const float* bb      = (const float*)d_in[6];
    const float* Wd_k    = (const float*)d_in[7];
    const float* Wd_r    = (const float*)d_in[8];
    const float* bd      = (const float*)d_in[9];
    const float* W_attn  = (const float*)d_in[10];
    const float* b_attn  = (const float*)d_in[11];
    const float* W_dense = (const float*)d_in[12];
    const float* b_dense = (const float*)d_in[13];
    float* out = (float*)d_out;

    float* ws = (float*)d_ws;
    // encoder/attn phase layout
    float* enc      = ws;                       // [0, ENC_N)
    float* attn_p   = ws + ENC_N;               // 65536
    float* hidden_p = ws + ENC_N + 65536;       // 65536
    float* xbuf_p   = ws + ENC_N + 131072;      // 640
    float* xconst_p = ws + ENC_N + 131712;      // 640
    // encoder-phase overlays (dead after encoder; attn_kernel then overwrites)
    float* h_ex_e   = ws + ENC_N;               // 131072 floats
    int*   cnt_e    = (int*)(ws + ENC_N + 131072); // 128 ints (overwritten later by xbuf)
    // decoder-phase overlays on dead enc region
    int*   cnt_d    = (int*)ws;                 // 64 ints
    float* h_ex_d   = ws + 4096;                // 131072 floats
    float* xpart_d  = ws + 4096 + 131072;       // 5120 floats

    hipMemsetAsync(cnt_e, 0, 128 * sizeof(int), stream);
    encoder_kernel<<<256, 1024, 0, stream>>>(x, Wf_k, Wf_r, bf, Wb_k, Wb_r, bb,
                                             enc, h_ex_e, cnt_e);
    attn_kernel<<<BATCH, 256, 0, stream>>>(enc, W_attn, b_attn, W_dense, b_dense, x,
                                           attn_p, hidden_p, xbuf_p, xconst_p);
    hipMemsetAsync(cnt_d, 0, 64 * sizeof(int), stream);
    decoder_kernel<<<256, 1024, 0, stream>>>(Wd_k, Wd_r, bd, W_dense,
                                             attn_p, hidden_p, xbuf_p, xconst_p,
                                             h_ex_d, xpart_d, cnt_d, out);
}